// Round 4
// baseline (264.809 us; speedup 1.0000x reference)
//
#include <hip/hip_runtime.h>

typedef unsigned short u16;
typedef __attribute__((ext_vector_type(8))) __bf16 bf16x8;
typedef __attribute__((ext_vector_type(2))) __bf16 bf16x2;
typedef __attribute__((ext_vector_type(4))) float f32x4;
typedef __attribute__((ext_vector_type(16))) float f32x16;

#define NB 2
#define NS 2048
#define ND 2048
#define NH 16
#define NKH 2
#define NHD 128
#define NQKV 2560
// 1/sqrt(128) * log2(e): scores in log2 domain -> exp2f = raw v_exp_f32
#define QSCALE (0.08838834764831845f * 1.4426950408889634f)

#define AS1 __attribute__((address_space(1)))
#define AS3 __attribute__((address_space(3)))

__device__ __forceinline__ u16 f2bf(float x) {
    union { float f; unsigned u; } v; v.f = x;
    unsigned r = v.u + 0x7fffu + ((v.u >> 16) & 1u);
    return (u16)(r >> 16);
}
__device__ __forceinline__ float bf2f(u16 x) {
    union { unsigned u; float f; } v; v.u = ((unsigned)x) << 16;
    return v.f;
}
__device__ __forceinline__ unsigned pk2(float lo, float hi_) {
    union { bf16x2 v; unsigned u; } t;
    t.v.x = (__bf16)lo; t.v.y = (__bf16)hi_;
    return t.u;
}

// ---------------- fp32 -> bf16 conversion (vectorized) ----------------
__global__ void cvt_kernel(const float* __restrict__ in, u16* __restrict__ out, int n4) {
    int i = blockIdx.x * 256 + threadIdx.x;
    if (i >= n4) return;
    float4 v = ((const float4*)in)[i];
    ushort4 o;
    o.x = f2bf(v.x); o.y = f2bf(v.y); o.z = f2bf(v.z); o.w = f2bf(v.w);
    ((ushort4*)out)[i] = o;
}

// ---------------- GEMM: C[M,N] = A[M,K] * B[N,K]^T (+bias) ----------------
template<int BIAS, int OUTBF16>
__global__ __launch_bounds__(256, 2)
void gemm_bt(const u16* __restrict__ A, const u16* __restrict__ B,
             const float* __restrict__ bias, void* __restrict__ Cout,
             int M, int N, int K)
{
    __shared__ u16 lds[2][2][8192];
    const int l = threadIdx.x & 63;
    const int w = threadIdx.x >> 6;
    const int m0 = blockIdx.x * 128, n0 = blockIdx.y * 128;
    const int wm = (w >> 1) * 64, wn = (w & 1) * 64;
    f32x4 acc[4][4] = {};

    const int lbyte = ((l & 7) * 16) ^ ((l >> 3) << 4);

    auto stage = [&](int buf, int k0) {
        #pragma unroll
        for (int inst = 0; inst < 4; ++inst) {
            int row = inst * 32 + w * 8 + (l >> 3);
            const u16* sa = A + (size_t)(m0 + row) * K + k0 + (lbyte >> 1);
            const u16* sb = B + (size_t)(n0 + row) * K + k0 + (lbyte >> 1);
            __builtin_amdgcn_global_load_lds(
                (const AS1 void*)sa,
                (AS3 void*)&lds[buf][0][inst * 2048 + w * 512], 16, 0, 0);
            __builtin_amdgcn_global_load_lds(
                (const AS1 void*)sb,
                (AS3 void*)&lds[buf][1][inst * 2048 + w * 512], 16, 0, 0);
        }
    };

    auto compute = [&](int buf) {
        const char* Ab = (const char*)&lds[buf][0][0];
        const char* Bb = (const char*)&lds[buf][1][0];
        #pragma unroll
        for (int kk = 0; kk < 2; ++kk) {
            int ac2 = kk * 64 + (l >> 4) * 16;
            bf16x8 af[4], bfr[4];
            #pragma unroll
            for (int i = 0; i < 4; ++i) {
                int ar = wm + i * 16 + (l & 15);
                af[i] = *(const bf16x8*)(Ab + ar * 128 + (ac2 ^ ((ar & 7) << 4)));
                int br = wn + i * 16 + (l & 15);
                bfr[i] = *(const bf16x8*)(Bb + br * 128 + (ac2 ^ ((br & 7) << 4)));
            }
            #pragma unroll
            for (int i = 0; i < 4; ++i)
                #pragma unroll
                for (int j = 0; j < 4; ++j)
                    acc[i][j] = __builtin_amdgcn_mfma_f32_16x16x32_bf16(af[i], bfr[j], acc[i][j], 0, 0, 0);
        }
    };

    stage(0, 0);
    const int NT = K >> 6;
    for (int kt = 0; kt < NT; ++kt) {
        __syncthreads();
        if (kt + 1 < NT) stage((kt + 1) & 1, (kt + 1) << 6);
        compute(kt & 1);
    }

    #pragma unroll
    for (int j = 0; j < 4; ++j) {
        int col = n0 + wn + j * 16 + (l & 15);
        float bv = BIAS ? bias[col] : 0.0f;
        #pragma unroll
        for (int i = 0; i < 4; ++i) {
            int row = m0 + wm + i * 16 + (l >> 4) * 4;
            #pragma unroll
            for (int r = 0; r < 4; ++r) {
                float v = acc[i][j][r] + bv;
                if (OUTBF16)
                    ((u16*)Cout)[(size_t)(row + r) * N + col] = f2bf(v);
                else
                    ((float*)Cout)[(size_t)(row + r) * N + col] = v;
            }
        }
    }
}

// ---------------- RoPE + scatter to attention layouts ----------------
__global__ void rope_scatter(const u16* __restrict__ qkv,
                             const float* __restrict__ cosb,
                             const float* __restrict__ sinb,
                             u16* __restrict__ Q, u16* __restrict__ Kb, u16* __restrict__ Vt)
{
    int idx = blockIdx.x * 256 + threadIdx.x;
    int c = idx % NQKV;
    int bs = idx / NQKV;
    int b = bs >> 11, s = bs & 2047;
    float x = bf2f(qkv[idx]);
    if (c < NH * NHD) {
        int h = c >> 7, d = c & 127;
        float cs = cosb[(size_t)bs * NHD + d];
        float sn = sinb[(size_t)bs * NHD + d];
        int pc = (c & ~127) | (d < 64 ? d + 64 : d - 64);
        float p = bf2f(qkv[(size_t)bs * NQKV + pc]);
        float v = x * cs + (d < 64 ? -p : p) * sn;
        Q[(((size_t)b * NH + h) * NS + s) * NHD + d] = f2bf(v * QSCALE);
    } else if (c < (NH + NKH) * NHD) {
        int cc = c - NH * NHD;
        int kh = cc >> 7, d = cc & 127;
        float cs = cosb[(size_t)bs * NHD + d];
        float sn = sinb[(size_t)bs * NHD + d];
        int pc = (c & ~127) | (d < 64 ? d + 64 : d - 64);
        float p = bf2f(qkv[(size_t)bs * NQKV + pc]);
        float v = x * cs + (d < 64 ? -p : p) * sn;
        Kb[(((size_t)b * NKH + kh) * NS + s) * NHD + d] = f2bf(v);
    } else {
        int cc = c - (NH + NKH) * NHD;
        int kh = cc >> 7, d = cc & 127;
        Vt[(((size_t)b * NKH + kh) * NHD + d) * NS + s] = qkv[idx];
    }
}

// ---------------- causal GQA flash attention v4 ----------------
// 1024 blocks x 2 waves; block=(hh, gg): 64 q-rows (wave w owns 32).
// LPT: gg = 31 - (i>>5) -> longest blocks dispatch first; hh = i&31 pins each
// (b,kh) KV stream to one XCD's L2 (blockIdx&7 == hh&7).
// K tiles (64 kv) double-buffered in LDS; V read directly from L2 (m169).
__global__ __launch_bounds__(128)
void attn_fwd4(const u16* __restrict__ Q, const u16* __restrict__ Kb,
               const u16* __restrict__ Vt, u16* __restrict__ Out)
{
    __shared__ u16 kl[2][8192];   // K tile: [64 rows][128 d] bf16 = 16 KB per buf

    const int l = threadIdx.x & 63;
    const int w = threadIdx.x >> 6;
    const int i = blockIdx.x;
    const int hh = i & 31;
    const int gg = 31 - (i >> 5);             // 0..31, long first
    const int h = hh & 15, b = hh >> 4;
    const int kh = h >> 3;
    const int c = l & 31, hi = l >> 5;
    const int q0 = gg * 64 + w * 32;          // this wave's 32 q-rows
    const int qend = q0 + 31;

    const u16* Qp = Q + (((size_t)b * NH + h) * NS + q0) * NHD;
    const u16* Kp = Kb + ((size_t)b * NKH + kh) * NS * NHD;
    const u16* Vp = Vt + ((size_t)b * NKH + kh) * (size_t)NHD * NS;

    // Q as B-fragments: col=q=c, k-dim=d: qf[ds] covers d = ds*16 + hi*8 + j
    bf16x8 qf[8];
    #pragma unroll
    for (int ds = 0; ds < 8; ++ds)
        qf[ds] = *(const bf16x8*)(Qp + c * NHD + ds * 16 + hi * 8);

    f32x16 o0 = {}, o1 = {}, o2 = {}, o3 = {};
    float m_run = -1e30f, l_run = 0.f;

    // stage one 64-kv K tile into buf: 16KB / 128 thr = 8 x 16B per thread
    auto stage = [&](int buf, int kt) {
        const int kb = kt << 6;
        #pragma unroll
        for (int ii = 0; ii < 8; ++ii) {
            int r = (w * 8 + ii) * 4 + (l >> 4);              // K row 0..63
            int q = (l & 15) ^ (r & 7);                       // swizzled col chunk
            const u16* src = Kp + (size_t)(kb + r) * NHD + q * 8;
            __builtin_amdgcn_global_load_lds(
                (const AS1 void*)src,
                (AS3 void*)&kl[buf][(w * 8 + ii) * 512], 16, 0, 0);
        }
    };

    const int NT = gg + 1;                     // KV tiles (block-uniform)
    stage(0, 0);
    __syncthreads();

    for (int kt = 0; kt < NT; ++kt) {
        const int kb = kt << 6;
        const int cur = kt & 1;
        if (kt + 1 < NT) stage(cur ^ 1, kt + 1);

        const bool do1 = (kb + 32 <= qend);    // sub-tile [kb+32, kb+64)
        const bool diag0 = (kb == q0);
        const bool diag1 = (kb + 32 == q0);
        const char* Klb = (const char*)kl[cur];

        f32x16 s0 = {}, s1 = {};
        #pragma unroll
        for (int ds = 0; ds < 8; ++ds) {
            bf16x8 kf0 = *(const bf16x8*)(Klb + c * 256 + ((ds * 32 + hi * 16) ^ ((c & 7) << 4)));
            s0 = __builtin_amdgcn_mfma_f32_32x32x16_bf16(kf0, qf[ds], s0, 0, 0, 0);
        }
        if (do1) {
            #pragma unroll
            for (int ds = 0; ds < 8; ++ds) {
                bf16x8 kf1 = *(const bf16x8*)(Klb + (32 + c) * 256 + ((ds * 32 + hi * 16) ^ ((c & 7) << 4)));
                s1 = __builtin_amdgcn_mfma_f32_32x32x16_bf16(kf1, qf[ds], s1, 0, 0, 0);
            }
        }

        float sv0[16], sv1[16];
        #pragma unroll
        for (int r = 0; r < 16; ++r) { sv0[r] = s0[r]; sv1[r] = do1 ? s1[r] : -1e30f; }

        if (diag0 || diag1) {                  // mask diagonal 32x32 sub-tile
            #pragma unroll
            for (int r = 0; r < 16; ++r) {
                int rr = (r & 3) + 8 * (r >> 2) + 4 * hi;
                if (diag0) { if (rr > c) sv0[r] = -1e30f; }
                else       { if (rr > c) sv1[r] = -1e30f; }
            }
        }

        float mx = -1e30f;
        #pragma unroll
        for (int r = 0; r < 16; ++r) mx = fmaxf(mx, fmaxf(sv0[r], sv1[r]));
        mx = fmaxf(mx, __shfl_xor(mx, 32));

        if (__any(mx > m_run + 8.0f)) {        // defer-max (T13)
            float mnew = fmaxf(m_run, mx);
            float alpha = exp2f(m_run - mnew);
            m_run = mnew;
            l_run *= alpha;
            #pragma unroll
            for (int r = 0; r < 16; ++r) {
                int qr = (r & 3) + 8 * (r >> 2) + 4 * hi;
                float aR = __shfl(alpha, qr + (l & 32));
                o0[r] *= aR; o1[r] *= aR; o2[r] *= aR; o3[r] *= aR;
            }
        }

        float e0[16], e1[16];
        float ls = 0.f;
        #pragma unroll
        for (int r = 0; r < 16; ++r) {
            e0[r] = exp2f(sv0[r] - m_run);
            e1[r] = exp2f(sv1[r] - m_run);
            ls += e0[r] + e1[r];
        }
        ls += __shfl_xor(ls, 32);
        l_run += ls;

        // P -> A-fragments (lane-half exchange)
        bf16x8 pa[4];
        #pragma unroll
        for (int ks = 0; ks < 4; ++ks) {
            const float* pe = (ks < 2) ? e0 : e1;
            const int b8 = (ks & 1) * 8;
            unsigned A  = pk2(pe[b8 + 0], pe[b8 + 1]);
            unsigned Bq = pk2(pe[b8 + 4], pe[b8 + 5]);
            unsigned C2 = pk2(pe[b8 + 2], pe[b8 + 3]);
            unsigned D2 = pk2(pe[b8 + 6], pe[b8 + 7]);
            unsigned sA = (unsigned)__shfl_xor((int)A, 32);
            unsigned sB = (unsigned)__shfl_xor((int)Bq, 32);
            unsigned sC = (unsigned)__shfl_xor((int)C2, 32);
            unsigned sD = (unsigned)__shfl_xor((int)D2, 32);
            union { uint4 u; bf16x8 v; } cv;
            cv.u.x = hi ? sB : A;
            cv.u.y = hi ? sD : C2;
            cv.u.z = hi ? Bq : sA;
            cv.u.w = hi ? D2 : sC;
            pa[ks] = cv.v;
        }

        // PV: V straight from global (Vt layout, contiguous 16B fragments)
        #pragma unroll
        for (int ks = 0; ks < 4; ++ks) {
            if (ks >= 2 && !do1) continue;
            const size_t vo = (size_t)kb + ks * 16 + hi * 8;
            bf16x8 vf;
            vf = *(const bf16x8*)(Vp + (size_t)(0 * 32 + c) * NS + vo);
            o0 = __builtin_amdgcn_mfma_f32_32x32x16_bf16(pa[ks], vf, o0, 0, 0, 0);
            vf = *(const bf16x8*)(Vp + (size_t)(1 * 32 + c) * NS + vo);
            o1 = __builtin_amdgcn_mfma_f32_32x32x16_bf16(pa[ks], vf, o1, 0, 0, 0);
            vf = *(const bf16x8*)(Vp + (size_t)(2 * 32 + c) * NS + vo);
            o2 = __builtin_amdgcn_mfma_f32_32x32x16_bf16(pa[ks], vf, o2, 0, 0, 0);
            vf = *(const bf16x8*)(Vp + (size_t)(3 * 32 + c) * NS + vo);
            o3 = __builtin_amdgcn_mfma_f32_32x32x16_bf16(pa[ks], vf, o3, 0, 0, 0);
        }
        __syncthreads();                       // next K tile staged & prior reads done
    }

    const float linv = 1.0f / l_run;
    #pragma unroll
    for (int r = 0; r < 16; ++r) {
        int qr = (r & 3) + 8 * (r >> 2) + 4 * hi;
        float lr = __shfl(linv, qr + (l & 32));
        size_t base = ((size_t)(b * NS + q0 + qr)) * (NH * NHD) + h * NHD;
        Out[base + c]      = f2bf(o0[r] * lr);
        Out[base + 32 + c] = f2bf(o1[r] * lr);
        Out[base + 64 + c] = f2bf(o2[r] * lr);
        Out[base + 96 + c] = f2bf(o3[r] * lr);
    }
}

// ---------------- host launcher ----------------
extern "C" void kernel_launch(void* const* d_in, const int* in_sizes, int n_in,
                              void* d_out, int out_size, void* d_ws, size_t ws_size,
                              hipStream_t stream)
{
    (void)in_sizes; (void)n_in; (void)out_size; (void)ws_size;
    const float* hidden = (const float*)d_in[0];
    const float* cosb   = (const float*)d_in[1];
    const float* sinb   = (const float*)d_in[2];
    const float* qkv_w  = (const float*)d_in[3];
    const float* qkv_b  = (const float*)d_in[4];
    const float* o_w    = (const float*)d_in[5];
    float* out = (float*)d_out;

    char* ws = (char*)d_ws;
    size_t off = 0;
    auto alloc = [&](size_t bytes) {
        void* p = ws + off; off += (bytes + 255) & ~(size_t)255; return p;
    };
    u16* hid_bf  = (u16*)alloc((size_t)NB * NS * ND * 2);
    u16* qkvw_bf = (u16*)alloc((size_t)NQKV * ND * 2);
    u16* ow_bf   = (u16*)alloc((size_t)ND * NH * NHD * 2);
    u16* qkv     = (u16*)alloc((size_t)NB * NS * NQKV * 2);
    u16* Qb      = (u16*)alloc((size_t)NB * NH * NS * NHD * 2);
    u16* Kb      = (u16*)alloc((size_t)NB * NKH * NS * NHD * 2);
    u16* Vt      = (u16*)alloc((size_t)NB * NKH * NS * NHD * 2);
    u16* attn    = hid_bf;   // alias: hidden_bf16 dead after GEMM1

    int n1 = NB * NS * ND / 4;
    cvt_kernel<<<(n1 + 255) / 256, 256, 0, stream>>>(hidden, hid_bf, n1);
    int n2 = NQKV * ND / 4;
    cvt_kernel<<<(n2 + 255) / 256, 256, 0, stream>>>(qkv_w, qkvw_bf, n2);
    int n3 = ND * NH * NHD / 4;
    cvt_kernel<<<(n3 + 255) / 256, 256, 0, stream>>>(o_w, ow_bf, n3);

    dim3 g1(NB * NS / 128, NQKV / 128);
    gemm_bt<1, 1><<<g1, 256, 0, stream>>>(hid_bf, qkvw_bf, qkv_b, qkv, NB * NS, NQKV, ND);

    int nr = NB * NS * NQKV;
    rope_scatter<<<nr / 256, 256, 0, stream>>>(qkv, cosb, sinb, Qb, Kb, Vt);

    attn_fwd4<<<1024, 128, 0, stream>>>(Qb, Kb, Vt, attn);

    dim3 g2(NB * NS / 128, ND / 128);
    gemm_bt<0, 0><<<g2, 256, 0, stream>>>(attn, ow_bf, nullptr, out, NB * NS, ND, NH * NHD);
}

// Round 5
// 218.933 us; speedup vs baseline: 1.2095x; 1.2095x over previous
//
#include <hip/hip_runtime.h>

typedef unsigned short u16;
typedef __attribute__((ext_vector_type(8))) __bf16 bf16x8;
typedef __attribute__((ext_vector_type(2))) __bf16 bf16x2;
typedef __attribute__((ext_vector_type(4))) float f32x4;
typedef __attribute__((ext_vector_type(16))) float f32x16;

#define NB 2
#define NS 2048
#define ND 2048
#define NH 16
#define NKH 2
#define NHD 128
#define NQKV 2560
// 1/sqrt(128) * log2(e): scores in log2 domain -> exp2f = raw v_exp_f32
#define QSCALE (0.08838834764831845f * 1.4426950408889634f)

#define AS1 __attribute__((address_space(1)))
#define AS3 __attribute__((address_space(3)))

__device__ __forceinline__ u16 f2bf(float x) {
    union { float f; unsigned u; } v; v.f = x;
    unsigned r = v.u + 0x7fffu + ((v.u >> 16) & 1u);
    return (u16)(r >> 16);
}
__device__ __forceinline__ float bf2f(u16 x) {
    union { unsigned u; float f; } v; v.u = ((unsigned)x) << 16;
    return v.f;
}
__device__ __forceinline__ unsigned pk2(float lo, float hi_) {
    union { bf16x2 v; unsigned u; } t;
    t.v.x = (__bf16)lo; t.v.y = (__bf16)hi_;
    return t.u;
}

// ---------------- fp32 -> bf16 conversion (vectorized) ----------------
__global__ void cvt_kernel(const float* __restrict__ in, u16* __restrict__ out, int n4) {
    int i = blockIdx.x * 256 + threadIdx.x;
    if (i >= n4) return;
    float4 v = ((const float4*)in)[i];
    ushort4 o;
    o.x = f2bf(v.x); o.y = f2bf(v.y); o.z = f2bf(v.z); o.w = f2bf(v.w);
    ((ushort4*)out)[i] = o;
}

// ---------------- GEMM: C[M,N] = A[M,K] * B[N,K]^T (+bias) ----------------
template<int BIAS, int OUTBF16>
__global__ __launch_bounds__(256, 2)
void gemm_bt(const u16* __restrict__ A, const u16* __restrict__ B,
             const float* __restrict__ bias, void* __restrict__ Cout,
             int M, int N, int K)
{
    __shared__ u16 lds[2][2][8192];
    const int l = threadIdx.x & 63;
    const int w = threadIdx.x >> 6;
    const int m0 = blockIdx.x * 128, n0 = blockIdx.y * 128;
    const int wm = (w >> 1) * 64, wn = (w & 1) * 64;
    f32x4 acc[4][4] = {};

    const int lbyte = ((l & 7) * 16) ^ ((l >> 3) << 4);

    auto stage = [&](int buf, int k0) {
        #pragma unroll
        for (int inst = 0; inst < 4; ++inst) {
            int row = inst * 32 + w * 8 + (l >> 3);
            const u16* sa = A + (size_t)(m0 + row) * K + k0 + (lbyte >> 1);
            const u16* sb = B + (size_t)(n0 + row) * K + k0 + (lbyte >> 1);
            __builtin_amdgcn_global_load_lds(
                (const AS1 void*)sa,
                (AS3 void*)&lds[buf][0][inst * 2048 + w * 512], 16, 0, 0);
            __builtin_amdgcn_global_load_lds(
                (const AS1 void*)sb,
                (AS3 void*)&lds[buf][1][inst * 2048 + w * 512], 16, 0, 0);
        }
    };

    auto compute = [&](int buf) {
        const char* Ab = (const char*)&lds[buf][0][0];
        const char* Bb = (const char*)&lds[buf][1][0];
        #pragma unroll
        for (int kk = 0; kk < 2; ++kk) {
            int ac2 = kk * 64 + (l >> 4) * 16;
            bf16x8 af[4], bfr[4];
            #pragma unroll
            for (int i = 0; i < 4; ++i) {
                int ar = wm + i * 16 + (l & 15);
                af[i] = *(const bf16x8*)(Ab + ar * 128 + (ac2 ^ ((ar & 7) << 4)));
                int br = wn + i * 16 + (l & 15);
                bfr[i] = *(const bf16x8*)(Bb + br * 128 + (ac2 ^ ((br & 7) << 4)));
            }
            #pragma unroll
            for (int i = 0; i < 4; ++i)
                #pragma unroll
                for (int j = 0; j < 4; ++j)
                    acc[i][j] = __builtin_amdgcn_mfma_f32_16x16x32_bf16(af[i], bfr[j], acc[i][j], 0, 0, 0);
        }
    };

    stage(0, 0);
    const int NT = K >> 6;
    for (int kt = 0; kt < NT; ++kt) {
        __syncthreads();
        if (kt + 1 < NT) stage((kt + 1) & 1, (kt + 1) << 6);
        compute(kt & 1);
    }

    #pragma unroll
    for (int j = 0; j < 4; ++j) {
        int col = n0 + wn + j * 16 + (l & 15);
        float bv = BIAS ? bias[col] : 0.0f;
        #pragma unroll
        for (int i = 0; i < 4; ++i) {
            int row = m0 + wm + i * 16 + (l >> 4) * 4;
            #pragma unroll
            for (int r = 0; r < 4; ++r) {
                float v = acc[i][j][r] + bv;
                if (OUTBF16)
                    ((u16*)Cout)[(size_t)(row + r) * N + col] = f2bf(v);
                else
                    ((float*)Cout)[(size_t)(row + r) * N + col] = v;
            }
        }
    }
}

// ---------------- RoPE + scatter to attention layouts ----------------
__global__ void rope_scatter(const u16* __restrict__ qkv,
                             const float* __restrict__ cosb,
                             const float* __restrict__ sinb,
                             u16* __restrict__ Q, u16* __restrict__ Kb, u16* __restrict__ Vt)
{
    int idx = blockIdx.x * 256 + threadIdx.x;
    int c = idx % NQKV;
    int bs = idx / NQKV;
    int b = bs >> 11, s = bs & 2047;
    float x = bf2f(qkv[idx]);
    if (c < NH * NHD) {
        int h = c >> 7, d = c & 127;
        float cs = cosb[(size_t)bs * NHD + d];
        float sn = sinb[(size_t)bs * NHD + d];
        int pc = (c & ~127) | (d < 64 ? d + 64 : d - 64);
        float p = bf2f(qkv[(size_t)bs * NQKV + pc]);
        float v = x * cs + (d < 64 ? -p : p) * sn;
        Q[(((size_t)b * NH + h) * NS + s) * NHD + d] = f2bf(v * QSCALE);
    } else if (c < (NH + NKH) * NHD) {
        int cc = c - NH * NHD;
        int kh = cc >> 7, d = cc & 127;
        float cs = cosb[(size_t)bs * NHD + d];
        float sn = sinb[(size_t)bs * NHD + d];
        int pc = (c & ~127) | (d < 64 ? d + 64 : d - 64);
        float p = bf2f(qkv[(size_t)bs * NQKV + pc]);
        float v = x * cs + (d < 64 ? -p : p) * sn;
        Kb[(((size_t)b * NKH + kh) * NS + s) * NHD + d] = f2bf(v);
    } else {
        int cc = c - (NH + NKH) * NHD;
        int kh = cc >> 7, d = cc & 127;
        Vt[(((size_t)b * NKH + kh) * NHD + d) * NS + s] = qkv[idx];
    }
}

// ---------------- causal GQA flash attention v5 ----------------
// v3 structure (4-wave blocks, K+V double-buffered LDS, swapped QK^T 32x32,
// in-register softmax) with balanced work assignment:
//   waves {0,1} own 64-row group gp, waves {2,3} own group 31-gp
//   (flip per dispatch sweep so heavy waves land on different SIMDs).
// Per-block active issue = (gp+1) + (32-gp) = 33 tiles, uniform; every
// iteration has >=2 compute-active waves. Sweep 1 = gp 0..7 (longest first),
// sweep 2 = gp 15..8, so co-resident pairs sum to NT 49 uniform.
__global__ __launch_bounds__(256, 2)
void attn_fwd5(const u16* __restrict__ Q, const u16* __restrict__ Kb,
               const u16* __restrict__ Vt, u16* __restrict__ Out)
{
    __shared__ u16 kl[2][8192];   // K tile: [64 rows][128 d] bf16, 16 KB per buf
    __shared__ u16 vl[2][8192];   // V tile: [128 d][64 kv] bf16, 16 KB per buf

    const int l = threadIdx.x & 63;
    const int w = threadIdx.x >> 6;
    const int i = blockIdx.x;
    const int s = i >> 8;                     // dispatch sweep 0/1
    const int j = i & 255;
    const int hh = j & 31;                    // b*16+h
    const int gp = s ? (15 - (j >> 5)) : (j >> 5);   // 0..15; long blocks first
    const int h = hh & 15, b = hh >> 4;
    const int kh = h >> 3;
    const int c = l & 31, hi = l >> 5;
    // wave -> 64-row group: {0,1}->lo, {2,3}->hi, flipped on sweep 2
    const int loWave = ((w >> 1) ^ s) == 0;
    const int grp = loWave ? gp : (31 - gp);
    const int q0 = grp * 64 + (w & 1) * 32;   // this wave's 32 q-rows
    const int qend = q0 + 31;

    const u16* Qp = Q + (((size_t)b * NH + h) * NS + q0) * NHD;
    const u16* Kp = Kb + ((size_t)b * NKH + kh) * NS * NHD;
    const u16* Vp = Vt + ((size_t)b * NKH + kh) * (size_t)NHD * NS;

    // Q as B-fragments: col=q=c, k-dim=d: qf[ds] covers d = ds*16 + hi*8 + j
    bf16x8 qf[8];
    #pragma unroll
    for (int ds = 0; ds < 8; ++ds)
        qf[ds] = *(const bf16x8*)(Qp + c * NHD + ds * 16 + hi * 8);

    f32x16 o0 = {}, o1 = {}, o2 = {}, o3 = {};
    float m_run = -1e30f, l_run = 0.f;

    // stage one 64-kv K/V tile pair into buf (8 global_load_lds per wave)
    auto stage = [&](int buf, int kt) {
        const int kb = kt << 6;
        #pragma unroll
        for (int ii = 0; ii < 4; ++ii) {           // K: rows r, swizzled col chunks
            int r = w * 16 + ii * 4 + (l >> 4);
            int q = (l & 15) ^ ((ii * 4 + (l >> 4)) & 7);
            const u16* src = Kp + (size_t)(kb + r) * NHD + q * 8;
            __builtin_amdgcn_global_load_lds(
                (const AS1 void*)src,
                (AS3 void*)&kl[buf][(w * 4 + ii) * 512], 16, 0, 0);
        }
        #pragma unroll
        for (int ii = 0; ii < 4; ++ii) {           // V: rows d, swizzled kv chunks
            int jj = w * 4 + ii;
            int d = jj * 8 + (l >> 3);
            int q = (l & 7) ^ ((l >> 3) & 7);
            const u16* src = Vp + (size_t)d * NS + kb + q * 8;
            __builtin_amdgcn_global_load_lds(
                (const AS1 void*)src,
                (AS3 void*)&vl[buf][jj * 512], 16, 0, 0);
        }
    };

    const int NT = 32 - gp;                    // covers hi group's kv range
    stage(0, 0);
    __syncthreads();

    for (int kt = 0; kt < NT; ++kt) {
        const int kb = kt << 6;
        const int cur = kt & 1;
        if (kt + 1 < NT) stage(cur ^ 1, kt + 1);

        const bool do0 = (kb <= qend);             // sub-tile [kb, kb+32)
        const bool do1 = (kb + 32 <= qend);        // sub-tile [kb+32, kb+64)
        if (do0) {
            const bool diag0 = (kb == q0);
            const bool diag1 = (kb + 32 == q0);
            const char* Klb = (const char*)kl[cur];
            const char* Vlb = (const char*)vl[cur];

            f32x16 s0 = {}, s1 = {};
            #pragma unroll
            for (int ds = 0; ds < 8; ++ds) {
                bf16x8 kf0 = *(const bf16x8*)(Klb + c * 256 + ((ds * 32 + hi * 16) ^ ((c & 7) << 4)));
                s0 = __builtin_amdgcn_mfma_f32_32x32x16_bf16(kf0, qf[ds], s0, 0, 0, 0);
            }
            if (do1) {
                #pragma unroll
                for (int ds = 0; ds < 8; ++ds) {
                    bf16x8 kf1 = *(const bf16x8*)(Klb + (32 + c) * 256 + ((ds * 32 + hi * 16) ^ ((c & 7) << 4)));
                    s1 = __builtin_amdgcn_mfma_f32_32x32x16_bf16(kf1, qf[ds], s1, 0, 0, 0);
                }
            }

            float sv0[16], sv1[16];
            #pragma unroll
            for (int r = 0; r < 16; ++r) { sv0[r] = s0[r]; sv1[r] = do1 ? s1[r] : -1e30f; }

            if (diag0 || diag1) {                  // mask diagonal 32x32 sub-tile
                #pragma unroll
                for (int r = 0; r < 16; ++r) {
                    int rr = (r & 3) + 8 * (r >> 2) + 4 * hi;
                    if (diag0) { if (rr > c) sv0[r] = -1e30f; }
                    else       { if (rr > c) sv1[r] = -1e30f; }
                }
            }

            float mx = -1e30f;
            #pragma unroll
            for (int r = 0; r < 16; ++r) mx = fmaxf(mx, fmaxf(sv0[r], sv1[r]));
            mx = fmaxf(mx, __shfl_xor(mx, 32));

            if (__any(mx > m_run + 8.0f)) {        // defer-max (T13)
                float mnew = fmaxf(m_run, mx);
                float alpha = exp2f(m_run - mnew);
                m_run = mnew;
                l_run *= alpha;
                #pragma unroll
                for (int r = 0; r < 16; ++r) {
                    int qr = (r & 3) + 8 * (r >> 2) + 4 * hi;
                    float aR = __shfl(alpha, qr + (l & 32));
                    o0[r] *= aR; o1[r] *= aR; o2[r] *= aR; o3[r] *= aR;
                }
            }

            float e0[16], e1[16];
            float ls = 0.f;
            #pragma unroll
            for (int r = 0; r < 16; ++r) {
                e0[r] = exp2f(sv0[r] - m_run);
                e1[r] = exp2f(sv1[r] - m_run);
                ls += e0[r] + e1[r];
            }
            ls += __shfl_xor(ls, 32);
            l_run += ls;

            // P -> A-fragments (lane-half exchange)
            bf16x8 pa[4];
            #pragma unroll
            for (int ks = 0; ks < 4; ++ks) {
                const float* pe = (ks < 2) ? e0 : e1;
                const int b8 = (ks & 1) * 8;
                unsigned A  = pk2(pe[b8 + 0], pe[b8 + 1]);
                unsigned Bq = pk2(pe[b8 + 4], pe[b8 + 5]);
                unsigned C2 = pk2(pe[b8 + 2], pe[b8 + 3]);
                unsigned D2 = pk2(pe[b8 + 6], pe[b8 + 7]);
                unsigned sA = (unsigned)__shfl_xor((int)A, 32);
                unsigned sB = (unsigned)__shfl_xor((int)Bq, 32);
                unsigned sC = (unsigned)__shfl_xor((int)C2, 32);
                unsigned sD = (unsigned)__shfl_xor((int)D2, 32);
                union { uint4 u; bf16x8 v; } cv;
                cv.u.x = hi ? sB : A;
                cv.u.y = hi ? sD : C2;
                cv.u.z = hi ? Bq : sA;
                cv.u.w = hi ? D2 : sC;
                pa[ks] = cv.v;
            }

            // PV from LDS V tile
            #pragma unroll
            for (int ks = 0; ks < 4; ++ks) {
                if (ks >= 2 && !do1) continue;
                const int ko = (ks * 32 + hi * 16);
                bf16x8 vf;
                vf = *(const bf16x8*)(Vlb + (0 * 32 + c) * 128 + (ko ^ ((c & 7) << 4)));
                o0 = __builtin_amdgcn_mfma_f32_32x32x16_bf16(pa[ks], vf, o0, 0, 0, 0);
                vf = *(const bf16x8*)(Vlb + (1 * 32 + c) * 128 + (ko ^ ((c & 7) << 4)));
                o1 = __builtin_amdgcn_mfma_f32_32x32x16_bf16(pa[ks], vf, o1, 0, 0, 0);
                vf = *(const bf16x8*)(Vlb + (2 * 32 + c) * 128 + (ko ^ ((c & 7) << 4)));
                o2 = __builtin_amdgcn_mfma_f32_32x32x16_bf16(pa[ks], vf, o2, 0, 0, 0);
                vf = *(const bf16x8*)(Vlb + (3 * 32 + c) * 128 + (ko ^ ((c & 7) << 4)));
                o3 = __builtin_amdgcn_mfma_f32_32x32x16_bf16(pa[ks], vf, o3, 0, 0, 0);
            }
        }
        __syncthreads();                           // drains vmcnt: next tile ready
    }

    const float linv = 1.0f / l_run;
    #pragma unroll
    for (int r = 0; r < 16; ++r) {
        int qr = (r & 3) + 8 * (r >> 2) + 4 * hi;
        float lr = __shfl(linv, qr + (l & 32));
        size_t base = ((size_t)(b * NS + q0 + qr)) * (NH * NHD) + h * NHD;
        Out[base + c]      = f2bf(o0[r] * lr);
        Out[base + 32 + c] = f2bf(o1[r] * lr);
        Out[base + 64 + c] = f2bf(o2[r] * lr);
        Out[base + 96 + c] = f2bf(o3[r] * lr);
    }
}

// ---------------- host launcher ----------------
extern "C" void kernel_launch(void* const* d_in, const int* in_sizes, int n_in,
                              void* d_out, int out_size, void* d_ws, size_t ws_size,
                              hipStream_t stream)
{
    (void)in_sizes; (void)n_in; (void)out_size; (void)ws_size;
    const float* hidden = (const float*)d_in[0];
    const float* cosb   = (const float*)d_in[1];
    const float* sinb   = (const float*)d_in[2];
    const float* qkv_w  = (const float*)d_in[3];
    const float* qkv_b  = (const float*)d_in[4];
    const float* o_w    = (const float*)d_in[5];
    float* out = (float*)d_out;

    char* ws = (char*)d_ws;
    size_t off = 0;
    auto alloc = [&](size_t bytes) {
        void* p = ws + off; off += (bytes + 255) & ~(size_t)255; return p;
    };
    u16* hid_bf  = (u16*)alloc((size_t)NB * NS * ND * 2);
    u16* qkvw_bf = (u16*)alloc((size_t)NQKV * ND * 2);
    u16* ow_bf   = (u16*)alloc((size_t)ND * NH * NHD * 2);
    u16* qkv     = (u16*)alloc((size_t)NB * NS * NQKV * 2);
    u16* Qb      = (u16*)alloc((size_t)NB * NH * NS * NHD * 2);
    u16* Kb      = (u16*)alloc((size_t)NB * NKH * NS * NHD * 2);
    u16* Vt      = (u16*)alloc((size_t)NB * NKH * NS * NHD * 2);
    u16* attn    = hid_bf;   // alias: hidden_bf16 dead after GEMM1

    int n1 = NB * NS * ND / 4;
    cvt_kernel<<<(n1 + 255) / 256, 256, 0, stream>>>(hidden, hid_bf, n1);
    int n2 = NQKV * ND / 4;
    cvt_kernel<<<(n2 + 255) / 256, 256, 0, stream>>>(qkv_w, qkvw_bf, n2);
    int n3 = ND * NH * NHD / 4;
    cvt_kernel<<<(n3 + 255) / 256, 256, 0, stream>>>(o_w, ow_bf, n3);

    dim3 g1(NB * NS / 128, NQKV / 128);
    gemm_bt<1, 1><<<g1, 256, 0, stream>>>(hid_bf, qkvw_bf, qkv_b, qkv, NB * NS, NQKV, ND);

    int nr = NB * NS * NQKV;
    rope_scatter<<<nr / 256, 256, 0, stream>>>(qkv, cosb, sinb, Qb, Kb, Vt);

    attn_fwd5<<<512, 256, 0, stream>>>(Qb, Kb, Vt, attn);

    dim3 g2(NB * NS / 128, ND / 128);
    gemm_bt<0, 0><<<g2, 256, 0, stream>>>(attn, ow_bf, nullptr, out, NB * NS, ND, NH * NHD);
}

// Round 6
// 216.998 us; speedup vs baseline: 1.2203x; 1.0089x over previous
//
#include <hip/hip_runtime.h>

typedef unsigned short u16;
typedef __attribute__((ext_vector_type(8))) __bf16 bf16x8;
typedef __attribute__((ext_vector_type(2))) __bf16 bf16x2;
typedef __attribute__((ext_vector_type(4))) float f32x4;
typedef __attribute__((ext_vector_type(16))) float f32x16;
typedef __attribute__((ext_vector_type(2))) unsigned u32x2;

#define NB 2
#define NS 2048
#define ND 2048
#define NH 16
#define NKH 2
#define NHD 128
#define NQKV 2560
// 1/sqrt(128) * log2(e): scores in log2 domain -> exp2f = raw v_exp_f32
#define QSCALE (0.08838834764831845f * 1.4426950408889634f)

#define AS1 __attribute__((address_space(1)))
#define AS3 __attribute__((address_space(3)))

__device__ __forceinline__ u16 f2bf(float x) {
    union { float f; unsigned u; } v; v.f = x;
    unsigned r = v.u + 0x7fffu + ((v.u >> 16) & 1u);
    return (u16)(r >> 16);
}
__device__ __forceinline__ float bf2f(u16 x) {
    union { unsigned u; float f; } v; v.u = ((unsigned)x) << 16;
    return v.f;
}
__device__ __forceinline__ unsigned pk2(float lo, float hi_) {
    union { bf16x2 v; unsigned u; } t;
    t.v.x = (__bf16)lo; t.v.y = (__bf16)hi_;
    return t.u;
}
// v_permlane32_swap_b32: a[32..63] <-> b[0..31].  After call:
//   a = {own lo-half | partner's b}, b = {partner's a | own hi-half}
__device__ __forceinline__ void pl32swap(unsigned &a, unsigned &b) {
#if __has_builtin(__builtin_amdgcn_permlane32_swap)
    u32x2 r = __builtin_amdgcn_permlane32_swap(a, b, false, false);
    a = r.x; b = r.y;
#else
    asm volatile("v_permlane32_swap_b32 %0, %1" : "+v"(a), "+v"(b));
#endif
}
__device__ __forceinline__ float fbits(unsigned u) {
    union { unsigned u; float f; } v; v.u = u; return v.f;
}
__device__ __forceinline__ unsigned ubits(float f) {
    union { float f; unsigned u; } v; v.f = f; return v.u;
}
// op(own, partner-across-lane^32) without ds_bpermute: duplicate + swap.
__device__ __forceinline__ float redmax32(float x) {
    unsigned a = ubits(x), b = a;
    pl32swap(a, b);                 // a={own,partner}, b={partner,own}
    return fmaxf(fbits(a), fbits(b));
}
__device__ __forceinline__ float redsum32(float x) {
    unsigned a = ubits(x), b = a;
    pl32swap(a, b);
    return fbits(a) + fbits(b);
}

// ---------------- fp32 -> bf16 conversion (vectorized) ----------------
__global__ void cvt_kernel(const float* __restrict__ in, u16* __restrict__ out, int n4) {
    int i = blockIdx.x * 256 + threadIdx.x;
    if (i >= n4) return;
    float4 v = ((const float4*)in)[i];
    ushort4 o;
    o.x = f2bf(v.x); o.y = f2bf(v.y); o.z = f2bf(v.z); o.w = f2bf(v.w);
    ((ushort4*)out)[i] = o;
}

// ---------------- GEMM: C[M,N] = A[M,K] * B[N,K]^T (+bias) ----------------
template<int BIAS, int OUTBF16>
__global__ __launch_bounds__(256, 2)
void gemm_bt(const u16* __restrict__ A, const u16* __restrict__ B,
             const float* __restrict__ bias, void* __restrict__ Cout,
             int M, int N, int K)
{
    __shared__ u16 lds[2][2][8192];
    const int l = threadIdx.x & 63;
    const int w = threadIdx.x >> 6;
    const int m0 = blockIdx.x * 128, n0 = blockIdx.y * 128;
    const int wm = (w >> 1) * 64, wn = (w & 1) * 64;
    f32x4 acc[4][4] = {};

    const int lbyte = ((l & 7) * 16) ^ ((l >> 3) << 4);

    auto stage = [&](int buf, int k0) {
        #pragma unroll
        for (int inst = 0; inst < 4; ++inst) {
            int row = inst * 32 + w * 8 + (l >> 3);
            const u16* sa = A + (size_t)(m0 + row) * K + k0 + (lbyte >> 1);
            const u16* sb = B + (size_t)(n0 + row) * K + k0 + (lbyte >> 1);
            __builtin_amdgcn_global_load_lds(
                (const AS1 void*)sa,
                (AS3 void*)&lds[buf][0][inst * 2048 + w * 512], 16, 0, 0);
            __builtin_amdgcn_global_load_lds(
                (const AS1 void*)sb,
                (AS3 void*)&lds[buf][1][inst * 2048 + w * 512], 16, 0, 0);
        }
    };

    auto compute = [&](int buf) {
        const char* Ab = (const char*)&lds[buf][0][0];
        const char* Bb = (const char*)&lds[buf][1][0];
        #pragma unroll
        for (int kk = 0; kk < 2; ++kk) {
            int ac2 = kk * 64 + (l >> 4) * 16;
            bf16x8 af[4], bfr[4];
            #pragma unroll
            for (int i = 0; i < 4; ++i) {
                int ar = wm + i * 16 + (l & 15);
                af[i] = *(const bf16x8*)(Ab + ar * 128 + (ac2 ^ ((ar & 7) << 4)));
                int br = wn + i * 16 + (l & 15);
                bfr[i] = *(const bf16x8*)(Bb + br * 128 + (ac2 ^ ((br & 7) << 4)));
            }
            #pragma unroll
            for (int i = 0; i < 4; ++i)
                #pragma unroll
                for (int j = 0; j < 4; ++j)
                    acc[i][j] = __builtin_amdgcn_mfma_f32_16x16x32_bf16(af[i], bfr[j], acc[i][j], 0, 0, 0);
        }
    };

    stage(0, 0);
    const int NT = K >> 6;
    for (int kt = 0; kt < NT; ++kt) {
        __syncthreads();
        if (kt + 1 < NT) stage((kt + 1) & 1, (kt + 1) << 6);
        compute(kt & 1);
    }

    #pragma unroll
    for (int j = 0; j < 4; ++j) {
        int col = n0 + wn + j * 16 + (l & 15);
        float bv = BIAS ? bias[col] : 0.0f;
        #pragma unroll
        for (int i = 0; i < 4; ++i) {
            int row = m0 + wm + i * 16 + (l >> 4) * 4;
            #pragma unroll
            for (int r = 0; r < 4; ++r) {
                float v = acc[i][j][r] + bv;
                if (OUTBF16)
                    ((u16*)Cout)[(size_t)(row + r) * N + col] = f2bf(v);
                else
                    ((float*)Cout)[(size_t)(row + r) * N + col] = v;
            }
        }
    }
}

// ---------------- RoPE + scatter to attention layouts ----------------
__global__ void rope_scatter(const u16* __restrict__ qkv,
                             const float* __restrict__ cosb,
                             const float* __restrict__ sinb,
                             u16* __restrict__ Q, u16* __restrict__ Kb, u16* __restrict__ Vt)
{
    int idx = blockIdx.x * 256 + threadIdx.x;
    int c = idx % NQKV;
    int bs = idx / NQKV;
    int b = bs >> 11, s = bs & 2047;
    float x = bf2f(qkv[idx]);
    if (c < NH * NHD) {
        int h = c >> 7, d = c & 127;
        float cs = cosb[(size_t)bs * NHD + d];
        float sn = sinb[(size_t)bs * NHD + d];
        int pc = (c & ~127) | (d < 64 ? d + 64 : d - 64);
        float p = bf2f(qkv[(size_t)bs * NQKV + pc]);
        float v = x * cs + (d < 64 ? -p : p) * sn;
        Q[(((size_t)b * NH + h) * NS + s) * NHD + d] = f2bf(v * QSCALE);
    } else if (c < (NH + NKH) * NHD) {
        int cc = c - NH * NHD;
        int kh = cc >> 7, d = cc & 127;
        float cs = cosb[(size_t)bs * NHD + d];
        float sn = sinb[(size_t)bs * NHD + d];
        int pc = (c & ~127) | (d < 64 ? d + 64 : d - 64);
        float p = bf2f(qkv[(size_t)bs * NQKV + pc]);
        float v = x * cs + (d < 64 ? -p : p) * sn;
        Kb[(((size_t)b * NKH + kh) * NS + s) * NHD + d] = f2bf(v);
    } else {
        int cc = c - (NH + NKH) * NHD;
        int kh = cc >> 7, d = cc & 127;
        Vt[(((size_t)b * NKH + kh) * NHD + d) * NS + s] = qkv[idx];
    }
}

// ---------------- causal GQA flash attention v6 ----------------
// v5 structure; cross-lane exchange via v_permlane32_swap (VALU, ~2cyc)
// instead of ds_bpermute (~120cyc) for P-pack and half-wave reductions;
// s_setprio(1) around MFMA clusters (T5).
__global__ __launch_bounds__(256, 2)
void attn_fwd6(const u16* __restrict__ Q, const u16* __restrict__ Kb,
               const u16* __restrict__ Vt, u16* __restrict__ Out)
{
    __shared__ u16 kl[2][8192];   // K tile: [64 rows][128 d] bf16, 16 KB per buf
    __shared__ u16 vl[2][8192];   // V tile: [128 d][64 kv] bf16, 16 KB per buf

    const int l = threadIdx.x & 63;
    const int w = threadIdx.x >> 6;
    const int i = blockIdx.x;
    const int s = i >> 8;                     // dispatch sweep 0/1
    const int j = i & 255;
    const int hh = j & 31;                    // b*16+h
    const int gp = s ? (15 - (j >> 5)) : (j >> 5);   // 0..15; long blocks first
    const int h = hh & 15, b = hh >> 4;
    const int kh = h >> 3;
    const int c = l & 31, hi = l >> 5;
    // wave -> 64-row group: {0,1}->lo, {2,3}->hi, flipped on sweep 2
    const int loWave = ((w >> 1) ^ s) == 0;
    const int grp = loWave ? gp : (31 - gp);
    const int q0 = grp * 64 + (w & 1) * 32;   // this wave's 32 q-rows
    const int qend = q0 + 31;

    const u16* Qp = Q + (((size_t)b * NH + h) * NS + q0) * NHD;
    const u16* Kp = Kb + ((size_t)b * NKH + kh) * NS * NHD;
    const u16* Vp = Vt + ((size_t)b * NKH + kh) * (size_t)NHD * NS;

    // Q as B-fragments: col=q=c, k-dim=d: qf[ds] covers d = ds*16 + hi*8 + j
    bf16x8 qf[8];
    #pragma unroll
    for (int ds = 0; ds < 8; ++ds)
        qf[ds] = *(const bf16x8*)(Qp + c * NHD + ds * 16 + hi * 8);

    f32x16 o0 = {}, o1 = {}, o2 = {}, o3 = {};
    float m_run = -1e30f, l_run = 0.f;

    // stage one 64-kv K/V tile pair into buf (8 global_load_lds per wave)
    auto stage = [&](int buf, int kt) {
        const int kb = kt << 6;
        #pragma unroll
        for (int ii = 0; ii < 4; ++ii) {           // K: rows r, swizzled col chunks
            int r = w * 16 + ii * 4 + (l >> 4);
            int q = (l & 15) ^ ((ii * 4 + (l >> 4)) & 7);
            const u16* src = Kp + (size_t)(kb + r) * NHD + q * 8;
            __builtin_amdgcn_global_load_lds(
                (const AS1 void*)src,
                (AS3 void*)&kl[buf][(w * 4 + ii) * 512], 16, 0, 0);
        }
        #pragma unroll
        for (int ii = 0; ii < 4; ++ii) {           // V: rows d, swizzled kv chunks
            int jj = w * 4 + ii;
            int d = jj * 8 + (l >> 3);
            int q = (l & 7) ^ ((l >> 3) & 7);
            const u16* src = Vp + (size_t)d * NS + kb + q * 8;
            __builtin_amdgcn_global_load_lds(
                (const AS1 void*)src,
                (AS3 void*)&vl[buf][jj * 512], 16, 0, 0);
        }
    };

    const int NT = 32 - gp;                    // covers hi group's kv range
    stage(0, 0);
    __syncthreads();

    for (int kt = 0; kt < NT; ++kt) {
        const int kb = kt << 6;
        const int cur = kt & 1;
        if (kt + 1 < NT) stage(cur ^ 1, kt + 1);

        const bool do0 = (kb <= qend);             // sub-tile [kb, kb+32)
        const bool do1 = (kb + 32 <= qend);        // sub-tile [kb+32, kb+64)
        if (do0) {
            const bool diag0 = (kb == q0);
            const bool diag1 = (kb + 32 == q0);
            const char* Klb = (const char*)kl[cur];
            const char* Vlb = (const char*)vl[cur];

            f32x16 s0 = {}, s1 = {};
            __builtin_amdgcn_s_setprio(1);
            #pragma unroll
            for (int ds = 0; ds < 8; ++ds) {
                bf16x8 kf0 = *(const bf16x8*)(Klb + c * 256 + ((ds * 32 + hi * 16) ^ ((c & 7) << 4)));
                s0 = __builtin_amdgcn_mfma_f32_32x32x16_bf16(kf0, qf[ds], s0, 0, 0, 0);
            }
            if (do1) {
                #pragma unroll
                for (int ds = 0; ds < 8; ++ds) {
                    bf16x8 kf1 = *(const bf16x8*)(Klb + (32 + c) * 256 + ((ds * 32 + hi * 16) ^ ((c & 7) << 4)));
                    s1 = __builtin_amdgcn_mfma_f32_32x32x16_bf16(kf1, qf[ds], s1, 0, 0, 0);
                }
            }
            __builtin_amdgcn_s_setprio(0);

            float sv0[16], sv1[16];
            #pragma unroll
            for (int r = 0; r < 16; ++r) { sv0[r] = s0[r]; sv1[r] = do1 ? s1[r] : -1e30f; }

            if (diag0 || diag1) {                  // mask diagonal 32x32 sub-tile
                #pragma unroll
                for (int r = 0; r < 16; ++r) {
                    int rr = (r & 3) + 8 * (r >> 2) + 4 * hi;
                    if (diag0) { if (rr > c) sv0[r] = -1e30f; }
                    else       { if (rr > c) sv1[r] = -1e30f; }
                }
            }

            float mx = -1e30f;
            #pragma unroll
            for (int r = 0; r < 16; ++r) mx = fmaxf(mx, fmaxf(sv0[r], sv1[r]));
            mx = redmax32(mx);                     // combine k-halves (VALU swap)

            if (__any(mx > m_run + 8.0f)) {        // defer-max (T13)
                float mnew = fmaxf(m_run, mx);
                float alpha = exp2f(m_run - mnew);
                m_run = mnew;
                l_run *= alpha;
                #pragma unroll
                for (int r = 0; r < 16; ++r) {
                    int qr = (r & 3) + 8 * (r >> 2) + 4 * hi;
                    float aR = __shfl(alpha, qr + (l & 32));
                    o0[r] *= aR; o1[r] *= aR; o2[r] *= aR; o3[r] *= aR;
                }
            }

            float e0[16], e1[16];
            float ls = 0.f;
            #pragma unroll
            for (int r = 0; r < 16; ++r) {
                e0[r] = exp2f(sv0[r] - m_run);
                e1[r] = exp2f(sv1[r] - m_run);
                ls += e0[r] + e1[r];
            }
            l_run += redsum32(ls);

            // P -> A-fragments: 2 permlane32_swap per ks (no bpermute/select).
            // After pl32swap(A,B): A = {own j0,1 | partner j0,1-for-hi},
            // B = {partner j4,5 | own j4,5} -> cv = {A, C, B, D} uniformly.
            bf16x8 pa[4];
            #pragma unroll
            for (int ks = 0; ks < 4; ++ks) {
                const float* pe = (ks < 2) ? e0 : e1;
                const int b8 = (ks & 1) * 8;
                unsigned A  = pk2(pe[b8 + 0], pe[b8 + 1]);
                unsigned Bq = pk2(pe[b8 + 4], pe[b8 + 5]);
                unsigned C2 = pk2(pe[b8 + 2], pe[b8 + 3]);
                unsigned D2 = pk2(pe[b8 + 6], pe[b8 + 7]);
                pl32swap(A, Bq);
                pl32swap(C2, D2);
                union { uint4 u; bf16x8 v; } cv;
                cv.u.x = A;
                cv.u.y = C2;
                cv.u.z = Bq;
                cv.u.w = D2;
                pa[ks] = cv.v;
            }

            // PV from LDS V tile
            __builtin_amdgcn_s_setprio(1);
            #pragma unroll
            for (int ks = 0; ks < 4; ++ks) {
                if (ks >= 2 && !do1) continue;
                const int ko = (ks * 32 + hi * 16);
                bf16x8 vf;
                vf = *(const bf16x8*)(Vlb + (0 * 32 + c) * 128 + (ko ^ ((c & 7) << 4)));
                o0 = __builtin_amdgcn_mfma_f32_32x32x16_bf16(pa[ks], vf, o0, 0, 0, 0);
                vf = *(const bf16x8*)(Vlb + (1 * 32 + c) * 128 + (ko ^ ((c & 7) << 4)));
                o1 = __builtin_amdgcn_mfma_f32_32x32x16_bf16(pa[ks], vf, o1, 0, 0, 0);
                vf = *(const bf16x8*)(Vlb + (2 * 32 + c) * 128 + (ko ^ ((c & 7) << 4)));
                o2 = __builtin_amdgcn_mfma_f32_32x32x16_bf16(pa[ks], vf, o2, 0, 0, 0);
                vf = *(const bf16x8*)(Vlb + (3 * 32 + c) * 128 + (ko ^ ((c & 7) << 4)));
                o3 = __builtin_amdgcn_mfma_f32_32x32x16_bf16(pa[ks], vf, o3, 0, 0, 0);
            }
            __builtin_amdgcn_s_setprio(0);
        }
        __syncthreads();                           // drains vmcnt: next tile ready
    }

    const float linv = 1.0f / l_run;
    #pragma unroll
    for (int r = 0; r < 16; ++r) {
        int qr = (r & 3) + 8 * (r >> 2) + 4 * hi;
        float lr = __shfl(linv, qr + (l & 32));
        size_t base = ((size_t)(b * NS + q0 + qr)) * (NH * NHD) + h * NHD;
        Out[base + c]      = f2bf(o0[r] * lr);
        Out[base + 32 + c] = f2bf(o1[r] * lr);
        Out[base + 64 + c] = f2bf(o2[r] * lr);
        Out[base + 96 + c] = f2bf(o3[r] * lr);
    }
}

// ---------------- host launcher ----------------
extern "C" void kernel_launch(void* const* d_in, const int* in_sizes, int n_in,
                              void* d_out, int out_size, void* d_ws, size_t ws_size,
                              hipStream_t stream)
{
    (void)in_sizes; (void)n_in; (void)out_size; (void)ws_size;
    const float* hidden = (const float*)d_in[0];
    const float* cosb   = (const float*)d_in[1];
    const float* sinb   = (const float*)d_in[2];
    const float* qkv_w  = (const float*)d_in[3];
    const float* qkv_b  = (const float*)d_in[4];
    const float* o_w    = (const float*)d_in[5];
    float* out = (float*)d_out;

    char* ws = (char*)d_ws;
    size_t off = 0;
    auto alloc = [&](size_t bytes) {
        void* p = ws + off; off += (bytes + 255) & ~(size_t)255; return p;
    };
    u16* hid_bf  = (u16*)alloc((size_t)NB * NS * ND * 2);
    u16* qkvw_bf = (u16*)alloc((size_t)NQKV * ND * 2);
    u16* ow_bf   = (u16*)alloc((size_t)ND * NH * NHD * 2);
    u16* qkv     = (u16*)alloc((size_t)NB * NS * NQKV * 2);
    u16* Qb      = (u16*)alloc((size_t)NB * NH * NS * NHD * 2);
    u16* Kb      = (u16*)alloc((size_t)NB * NKH * NS * NHD * 2);
    u16* Vt      = (u16*)alloc((size_t)NB * NKH * NS * NHD * 2);
    u16* attn    = hid_bf;   // alias: hidden_bf16 dead after GEMM1

    int n1 = NB * NS * ND / 4;
    cvt_kernel<<<(n1 + 255) / 256, 256, 0, stream>>>(hidden, hid_bf, n1);
    int n2 = NQKV * ND / 4;
    cvt_kernel<<<(n2 + 255) / 256, 256, 0, stream>>>(qkv_w, qkvw_bf, n2);
    int n3 = ND * NH * NHD / 4;
    cvt_kernel<<<(n3 + 255) / 256, 256, 0, stream>>>(o_w, ow_bf, n3);

    dim3 g1(NB * NS / 128, NQKV / 128);
    gemm_bt<1, 1><<<g1, 256, 0, stream>>>(hid_bf, qkvw_bf, qkv_b, qkv, NB * NS, NQKV, ND);

    int nr = NB * NS * NQKV;
    rope_scatter<<<nr / 256, 256, 0, stream>>>(qkv, cosb, sinb, Qb, Kb, Vt);

    attn_fwd6<<<512, 256, 0, stream>>>(Qb, Kb, Vt, attn);

    dim3 g2(NB * NS / 128, ND / 128);
    gemm_bt<0, 0><<<g2, 256, 0, stream>>>(attn, ow_bf, nullptr, out, NB * NS, ND, NH * NHD);
}